// Round 4
// baseline (3123.413 us; speedup 1.0000x reference)
//
#include <hip/hip_runtime.h>

#define TT 4000   // timesteps
#define HH 64     // hidden
#define NB 256    // batch
#define EE 128    // fc out
#define KQ 16     // per-thread reduction quarter

// Fast activations: v_exp_f32 + v_rcp_f32. ~1e-6 rel err vs 3.4e-3 threshold.
__device__ __forceinline__ float fsig(float x) {
    return __builtin_amdgcn_rcpf(1.f + __expf(-x));
}
__device__ __forceinline__ float ftanh(float x) {
    return fmaf(2.f, __builtin_amdgcn_rcpf(1.f + __expf(-2.f * x)), -1.f);
}

// One block (1024 thr) per batch element. Threads 4r..4r+3 own gate row r
// (i,f,g,o over r=0..255) split along k in quarters of 16 for all three
// recurrent matrices -> 48 weight floats/thread. R2/R3 showed the allocator
// pins to ~85-90 VGPRs and spills/refetches anything bigger (R3: VGPR=88 with
// a 96-float footprint, weights streamed from L2 every step, VALUBusy 55%).
// 48 floats + working set fits the envelope by construction.
//
// Layer pipelining (as R3): iteration t computes L0 gates(t) from h0(t-1) and
// L1 gates(t-1) from {h1(t-2), h0(t-1)} in one phase; wave0 updates c0(t),
// wave1 updates c1(t-1). 2 barriers/step. Quad-reduce via __shfl_xor 1,2.
__global__ __launch_bounds__(1024) __attribute__((amdgpu_waves_per_eu(4, 4)))
void lstm2_fc_kernel(const float* __restrict__ x,      // [B, T, 1]
                     const float* __restrict__ W_ih0,  // [256, 1]
                     const float* __restrict__ W_hh0,  // [256, 64]
                     const float* __restrict__ b_ih0,  // [256]
                     const float* __restrict__ b_hh0,  // [256]
                     const float* __restrict__ W_ih1,  // [256, 64]
                     const float* __restrict__ W_hh1,  // [256, 64]
                     const float* __restrict__ b_ih1,  // [256]
                     const float* __restrict__ b_hh1,  // [256]
                     const float* __restrict__ W_fc,   // [128, 64]
                     const float* __restrict__ b_fc,   // [128]
                     float* __restrict__ out)          // [B, 128]
{
    const int b   = blockIdx.x;
    const int tid = threadIdx.x;    // 0..1023
    const int r   = tid >> 2;       // gate row 0..255
    const int q   = tid & 3;        // k-quarter
    const int jb  = q * (KQ / 4);   // float4 base index into h vectors

    __shared__ float x_s[TT];          // 16 KB
    __shared__ float h0_s[HH];         // h0(t-1) at phase start
    __shared__ float h1_s[HH];         // h1(t-2) at phase start
    __shared__ float g0_s[4 * HH];     // L0 gate activations
    __shared__ float g1_s[4 * HH];     // L1 gate activations

    for (int t = tid; t < TT; t += 1024) x_s[t] = x[(size_t)b * TT + t];

    // 3 quarter-rows of weights -> VGPRs (48 floats).
    float w_hh0[KQ], w_ih1[KQ], w_hh1[KQ];
    {
        const float4* p0 = (const float4*)(W_hh0 + r * HH + q * KQ);
        const float4* p1 = (const float4*)(W_ih1 + r * HH + q * KQ);
        const float4* p2 = (const float4*)(W_hh1 + r * HH + q * KQ);
        #pragma unroll
        for (int k = 0; k < KQ / 4; ++k) {
            float4 v0 = p0[k], v1 = p1[k], v2 = p2[k];
            w_hh0[4*k+0] = v0.x; w_hh0[4*k+1] = v0.y; w_hh0[4*k+2] = v0.z; w_hh0[4*k+3] = v0.w;
            w_ih1[4*k+0] = v1.x; w_ih1[4*k+1] = v1.y; w_ih1[4*k+2] = v1.z; w_ih1[4*k+3] = v1.w;
            w_hh1[4*k+0] = v2.x; w_hh1[4*k+1] = v2.y; w_hh1[4*k+2] = v2.z; w_hh1[4*k+3] = v2.w;
        }
    }
    const float wx  = W_ih0[r];
    const float bb0 = b_ih0[r] + b_hh0[r];
    const float bb1 = b_ih1[r] + b_hh1[r];
    const int gate_type = r >> 6;      // wave-uniform (16 rows/wave, gate blocks of 64)

    float c0 = 0.f, c1 = 0.f;          // c0 live in wave0, c1 in wave1
    if (tid < HH) { h0_s[tid] = 0.f; h1_s[tid] = 0.f; }
    __syncthreads();

    const float4* h0v = (const float4*)h0_s;
    const float4* h1v = (const float4*)h1_s;

    // TT+1 iterations: L0 active for t<TT, L1 (one step behind) for t>0.
    for (int t = 0; t <= TT; ++t) {
        const float xt = x_s[(t < TT) ? t : 0];   // broadcast; unused at t=TT

        float acc0 = (q == 0) ? fmaf(xt, wx, bb0) : 0.f;
        float acc1 = (q == 0) ? bb1 : 0.f;
        #pragma unroll
        for (int j = 0; j < KQ / 4; ++j) {
            float4 h0x = h0v[jb + j];             // 4-addr broadcast b128
            float4 h1x = h1v[jb + j];
            acc0 = fmaf(w_hh0[4*j+0], h0x.x, acc0);
            acc0 = fmaf(w_hh0[4*j+1], h0x.y, acc0);
            acc0 = fmaf(w_hh0[4*j+2], h0x.z, acc0);
            acc0 = fmaf(w_hh0[4*j+3], h0x.w, acc0);
            acc1 = fmaf(w_ih1[4*j+0], h0x.x, acc1);
            acc1 = fmaf(w_ih1[4*j+1], h0x.y, acc1);
            acc1 = fmaf(w_ih1[4*j+2], h0x.z, acc1);
            acc1 = fmaf(w_ih1[4*j+3], h0x.w, acc1);
            acc1 = fmaf(w_hh1[4*j+0], h1x.x, acc1);
            acc1 = fmaf(w_hh1[4*j+1], h1x.y, acc1);
            acc1 = fmaf(w_hh1[4*j+2], h1x.z, acc1);
            acc1 = fmaf(w_hh1[4*j+3], h1x.w, acc1);
        }
        // Quad reduce (lanes 4r..4r+3, DPP).
        acc0 += __shfl_xor(acc0, 1);
        acc0 += __shfl_xor(acc0, 2);
        acc1 += __shfl_xor(acc1, 1);
        acc1 += __shfl_xor(acc1, 2);
        if (q == 0) {                             // 16 lanes/wave -> 16 banks
            g0_s[r] = (gate_type == 2) ? ftanh(acc0) : fsig(acc0);
            g1_s[r] = (gate_type == 2) ? ftanh(acc1) : fsig(acc1);
        }
        __syncthreads();                          // B1: gates visible; h reads drained

        if (tid < HH) {                           // wave 0: L0 cell (time t)
            if (t < TT) {
                float iv = g0_s[tid];
                float fv = g0_s[HH + tid];
                float gv = g0_s[2 * HH + tid];
                float ov = g0_s[3 * HH + tid];
                c0 = fmaf(fv, c0, iv * gv);
                h0_s[tid] = ov * ftanh(c0);
            }
        } else if (tid < 2 * HH) {                // wave 1: L1 cell (time t-1)
            if (t > 0) {
                int j = tid - HH;
                float iv = g1_s[j];
                float fv = g1_s[HH + j];
                float gv = g1_s[2 * HH + j];
                float ov = g1_s[3 * HH + j];
                c1 = fmaf(fv, c1, iv * gv);
                h1_s[j] = ov * ftanh(c1);
            }
        }
        __syncthreads();                          // B2: new h0/h1 visible
    }

    // FC on final h1 = h1(TT-1): out[b, e] = W_fc[e,:] . h1 + b_fc[e]
    if (tid < EE) {
        float acc = b_fc[tid];
        const float4* wf = (const float4*)(W_fc + tid * HH);
        #pragma unroll
        for (int k = 0; k < HH / 4; ++k) {
            float4 v = wf[k];
            acc = fmaf(v.x, h1_s[4*k+0], acc);
            acc = fmaf(v.y, h1_s[4*k+1], acc);
            acc = fmaf(v.z, h1_s[4*k+2], acc);
            acc = fmaf(v.w, h1_s[4*k+3], acc);
        }
        out[(size_t)b * EE + tid] = acc;
    }
}

extern "C" void kernel_launch(void* const* d_in, const int* in_sizes, int n_in,
                              void* d_out, int out_size, void* d_ws, size_t ws_size,
                              hipStream_t stream) {
    const float* x     = (const float*)d_in[0];
    const float* W_ih0 = (const float*)d_in[1];
    const float* W_hh0 = (const float*)d_in[2];
    const float* b_ih0 = (const float*)d_in[3];
    const float* b_hh0 = (const float*)d_in[4];
    const float* W_ih1 = (const float*)d_in[5];
    const float* W_hh1 = (const float*)d_in[6];
    const float* b_ih1 = (const float*)d_in[7];
    const float* b_hh1 = (const float*)d_in[8];
    const float* W_fc  = (const float*)d_in[9];
    const float* b_fc  = (const float*)d_in[10];
    float* out = (float*)d_out;

    lstm2_fc_kernel<<<dim3(NB), dim3(1024), 0, stream>>>(
        x, W_ih0, W_hh0, b_ih0, b_hh0, W_ih1, W_hh1, b_ih1, b_hh1, W_fc, b_fc, out);
}

// Round 5
// 2699.241 us; speedup vs baseline: 1.1571x; 1.1571x over previous
//
#include <hip/hip_runtime.h>

#define TT 4000   // timesteps
#define HH 64     // hidden
#define NB 256    // batch
#define EE 128    // fc out
#define KQ 16     // per-thread reduction quarter (16 halves = 8 half2)

typedef __attribute__((ext_vector_type(2))) _Float16 h2;

// Fast activations: v_exp_f32 + v_rcp_f32. ~1e-6 rel err vs 3.4e-3 threshold.
__device__ __forceinline__ float fsig(float x) {
    return __builtin_amdgcn_rcpf(1.f + __expf(-x));
}
__device__ __forceinline__ float ftanh(float x) {
    return fmaf(2.f, __builtin_amdgcn_rcpf(1.f + __expf(-2.f * x)), -1.f);
}

#if __has_builtin(__builtin_amdgcn_fdot2)
#define FDOT2(a, b, c) __builtin_amdgcn_fdot2((a), (b), (c), false)
#else
#define FDOT2(a, b, c) fmaf((float)(a).x, (float)(b).x, fmaf((float)(a).y, (float)(b).y, (c)))
#endif

// One block (1024 thr) per batch element. Threads 4r..4r+3 own gate row r
// (i,f,g,o over r=0..255) split along k in quarters of 16 for all three
// recurrent matrices. R1-R4 evidence: the allocator pins this kernel to
// ~64-88 VGPRs no matter what hints we give, so fp32 weight arrays (48-96
// floats) always spill and get refetched every timestep. Fix: fp16 weights
// packed in half2 -> 24 weight VGPRs via v_dot2_f32_f16 (fp32 accumulate).
// Total footprint ~55-60 regs fits the 64-reg envelope by construction.
// Only weights + h are fp16; x-term, biases, gates, c stay fp32.
//
// Layer pipelining (verified R3/R4): iteration t computes L0 gates(t) from
// h0(t-1) and L1 gates(t-1) from {h1(t-2), h0(t-1)} in one phase; wave0
// updates c0(t), wave1 updates c1(t-1). 2 barriers/step.
__global__ __launch_bounds__(1024, 4)
void lstm2_fc_kernel(const float* __restrict__ x,      // [B, T, 1]
                     const float* __restrict__ W_ih0,  // [256, 1]
                     const float* __restrict__ W_hh0,  // [256, 64]
                     const float* __restrict__ b_ih0,  // [256]
                     const float* __restrict__ b_hh0,  // [256]
                     const float* __restrict__ W_ih1,  // [256, 64]
                     const float* __restrict__ W_hh1,  // [256, 64]
                     const float* __restrict__ b_ih1,  // [256]
                     const float* __restrict__ b_hh1,  // [256]
                     const float* __restrict__ W_fc,   // [128, 64]
                     const float* __restrict__ b_fc,   // [128]
                     float* __restrict__ out)          // [B, 128]
{
    const int b   = blockIdx.x;
    const int tid = threadIdx.x;    // 0..1023
    const int r   = tid >> 2;       // gate row 0..255
    const int q   = tid & 3;        // k-quarter

    __shared__ float x_s[TT];                       // 16 KB
    __shared__ __align__(16) _Float16 h0_h[HH];     // h0(t-1), fp16
    __shared__ __align__(16) _Float16 h1_h[HH];     // h1(t-2), fp16
    __shared__ float g0_s[4 * HH];                  // L0 gate activations (fp32)
    __shared__ float g1_s[4 * HH];                  // L1 gate activations (fp32)

    for (int t = tid; t < TT; t += 1024) x_s[t] = x[(size_t)b * TT + t];

    // 3 quarter-rows of weights -> fp16 packed VGPRs (24 half2).
    h2 w0[KQ / 2], wi1[KQ / 2], wh1[KQ / 2];
    {
        const float4* p0 = (const float4*)(W_hh0 + r * HH + q * KQ);
        const float4* p1 = (const float4*)(W_ih1 + r * HH + q * KQ);
        const float4* p2 = (const float4*)(W_hh1 + r * HH + q * KQ);
        #pragma unroll
        for (int k = 0; k < KQ / 4; ++k) {
            float4 v0 = p0[k], v1 = p1[k], v2 = p2[k];
            w0 [2*k+0] = h2{(_Float16)v0.x, (_Float16)v0.y};
            w0 [2*k+1] = h2{(_Float16)v0.z, (_Float16)v0.w};
            wi1[2*k+0] = h2{(_Float16)v1.x, (_Float16)v1.y};
            wi1[2*k+1] = h2{(_Float16)v1.z, (_Float16)v1.w};
            wh1[2*k+0] = h2{(_Float16)v2.x, (_Float16)v2.y};
            wh1[2*k+1] = h2{(_Float16)v2.z, (_Float16)v2.w};
        }
    }
    const float wx  = W_ih0[r];
    const float bb0 = b_ih0[r] + b_hh0[r];
    const float bb1 = b_ih1[r] + b_hh1[r];
    const int gate_type = r >> 6;      // wave-uniform (16 rows/wave)

    float c0 = 0.f, c1 = 0.f;          // c0 live in wave0, c1 in wave1
    if (tid < HH) { h0_h[tid] = (_Float16)0.f; h1_h[tid] = (_Float16)0.f; }
    __syncthreads();

    const float4* h0v = (const float4*)h0_h;   // 8 halves per float4
    const float4* h1v = (const float4*)h1_h;

    // TT+1 iterations: L0 active for t<TT, L1 (one step behind) for t>0.
    for (int t = 0; t <= TT; ++t) {
        const float xt = x_s[(t < TT) ? t : 0];   // broadcast; unused at t=TT

        float acc0 = (q == 0) ? fmaf(xt, wx, bb0) : 0.f;
        float a1a  = (q == 0) ? bb1 : 0.f;        // W_ih1 . h0 chain
        float a1b  = 0.f;                         // W_hh1 . h1 chain

        // This thread's 16-half slices of h0 and h1 (2x b128 broadcast each).
        float4 H0a = h0v[q * 2 + 0], H0b = h0v[q * 2 + 1];
        float4 H1a = h1v[q * 2 + 0], H1b = h1v[q * 2 + 1];
        const h2* ph0 = (const h2*)&H0a;   // 8 half2 spanning H0a,H0b
        const h2* ph1 = (const h2*)&H1a;   // (contiguous locals)

        #pragma unroll
        for (int j = 0; j < 4; ++j) {
            acc0 = FDOT2(w0 [j], ph0[j], acc0);
            a1a  = FDOT2(wi1[j], ph0[j], a1a);
            a1b  = FDOT2(wh1[j], ph1[j], a1b);
        }
        const h2* ph0b = (const h2*)&H0b;
        const h2* ph1b = (const h2*)&H1b;
        #pragma unroll
        for (int j = 0; j < 4; ++j) {
            acc0 = FDOT2(w0 [4 + j], ph0b[j], acc0);
            a1a  = FDOT2(wi1[4 + j], ph0b[j], a1a);
            a1b  = FDOT2(wh1[4 + j], ph1b[j], a1b);
        }
        float acc1 = a1a + a1b;

        // Quad reduce (lanes 4r..4r+3, DPP).
        acc0 += __shfl_xor(acc0, 1);
        acc0 += __shfl_xor(acc0, 2);
        acc1 += __shfl_xor(acc1, 1);
        acc1 += __shfl_xor(acc1, 2);
        if (q == 0) {
            g0_s[r] = (gate_type == 2) ? ftanh(acc0) : fsig(acc0);
            g1_s[r] = (gate_type == 2) ? ftanh(acc1) : fsig(acc1);
        }
        __syncthreads();                          // B1: gates visible; h reads drained

        if (tid < HH) {                           // wave 0: L0 cell (time t)
            if (t < TT) {
                float iv = g0_s[tid];
                float fv = g0_s[HH + tid];
                float gv = g0_s[2 * HH + tid];
                float ov = g0_s[3 * HH + tid];
                c0 = fmaf(fv, c0, iv * gv);
                h0_h[tid] = (_Float16)(ov * ftanh(c0));
            }
        } else if (tid < 2 * HH) {                // wave 1: L1 cell (time t-1)
            if (t > 0) {
                int j = tid - HH;
                float iv = g1_s[j];
                float fv = g1_s[HH + j];
                float gv = g1_s[2 * HH + j];
                float ov = g1_s[3 * HH + j];
                c1 = fmaf(fv, c1, iv * gv);
                h1_h[j] = (_Float16)(ov * ftanh(c1));
            }
        }
        __syncthreads();                          // B2: new h0/h1 visible
    }

    // FC on final h1 = h1(TT-1): out[b, e] = W_fc[e,:] . h1 + b_fc[e]
    if (tid < EE) {
        float acc = b_fc[tid];
        const float4* wf = (const float4*)(W_fc + tid * HH);
        #pragma unroll
        for (int k = 0; k < HH / 4; ++k) {
            float4 v = wf[k];
            acc = fmaf(v.x, (float)h1_h[4*k+0], acc);
            acc = fmaf(v.y, (float)h1_h[4*k+1], acc);
            acc = fmaf(v.z, (float)h1_h[4*k+2], acc);
            acc = fmaf(v.w, (float)h1_h[4*k+3], acc);
        }
        out[(size_t)b * EE + tid] = acc;
    }
}

extern "C" void kernel_launch(void* const* d_in, const int* in_sizes, int n_in,
                              void* d_out, int out_size, void* d_ws, size_t ws_size,
                              hipStream_t stream) {
    const float* x     = (const float*)d_in[0];
    const float* W_ih0 = (const float*)d_in[1];
    const float* W_hh0 = (const float*)d_in[2];
    const float* b_ih0 = (const float*)d_in[3];
    const float* b_hh0 = (const float*)d_in[4];
    const float* W_ih1 = (const float*)d_in[5];
    const float* W_hh1 = (const float*)d_in[6];
    const float* b_ih1 = (const float*)d_in[7];
    const float* b_hh1 = (const float*)d_in[8];
    const float* W_fc  = (const float*)d_in[9];
    const float* b_fc  = (const float*)d_in[10];
    float* out = (float*)d_out;

    lstm2_fc_kernel<<<dim3(NB), dim3(1024), 0, stream>>>(
        x, W_ih0, W_hh0, b_ih0, b_hh0, W_ih1, W_hh1, b_ih1, b_hh1, W_fc, b_fc, out);
}

// Round 6
// 2695.409 us; speedup vs baseline: 1.1588x; 1.0014x over previous
//
#include <hip/hip_runtime.h>

#define TT 4000   // timesteps
#define HH 64     // hidden
#define NB 256    // batch
#define EE 128    // fc out
#define KQ 16     // per-thread reduction quarter (16 halves = 8 half2)

typedef __attribute__((ext_vector_type(2))) _Float16 h2;

// Fast activations: v_exp_f32 + v_rcp_f32. ~1e-6 rel err vs 3.4e-3 threshold.
__device__ __forceinline__ float fsig(float x) {
    return __builtin_amdgcn_rcpf(1.f + __expf(-x));
}
__device__ __forceinline__ float ftanh(float x) {
    return fmaf(2.f, __builtin_amdgcn_rcpf(1.f + __expf(-2.f * x)), -1.f);
}

#if __has_builtin(__builtin_amdgcn_fdot2)
#define FDOT2(a, b, c) __builtin_amdgcn_fdot2((a), (b), (c), false)
#else
#define FDOT2(a, b, c) fmaf((float)(a).x, (float)(b).x, fmaf((float)(a).y, (float)(b).y, (c)))
#endif

// One block (1024 thr) per batch element. Threads 4r..4r+3 own gate row r
// (i,f,g,o over r=0..255) split along k in quarters of 16 for all three
// recurrent matrices; weights as fp16 half2 + v_dot2_f32_f16 (fp32 accum).
//
// R5 finding: VGPR_Count=36 — LLVM SINKS the loop-invariant weight loads into
// the t-loop (remat from L2 every step: 98 KB/block/step ≈ 1750 cyc at L2 BW,
// matching the measured 1620 cyc/step). Fix: empty asm volatile "+v" pins the
// 24 weight half2 in VGPRs so the loads cannot be rematerialized. ~60 live
// regs, budget 128 (grid=256 on 256 CUs -> 1 block/CU regardless).
//
// Layer pipelining (verified R3-R5): iteration t computes L0 gates(t) from
// h0(t-1) and L1 gates(t-1) from {h1(t-2), h0(t-1)} in one phase; wave0
// updates c0(t), wave1 updates c1(t-1). 2 barriers/step.
__global__ __launch_bounds__(1024, 4)
void lstm2_fc_kernel(const float* __restrict__ x,      // [B, T, 1]
                     const float* __restrict__ W_ih0,  // [256, 1]
                     const float* __restrict__ W_hh0,  // [256, 64]
                     const float* __restrict__ b_ih0,  // [256]
                     const float* __restrict__ b_hh0,  // [256]
                     const float* __restrict__ W_ih1,  // [256, 64]
                     const float* __restrict__ W_hh1,  // [256, 64]
                     const float* __restrict__ b_ih1,  // [256]
                     const float* __restrict__ b_hh1,  // [256]
                     const float* __restrict__ W_fc,   // [128, 64]
                     const float* __restrict__ b_fc,   // [128]
                     float* __restrict__ out)          // [B, 128]
{
    const int b   = blockIdx.x;
    const int tid = threadIdx.x;    // 0..1023
    const int r   = tid >> 2;       // gate row 0..255
    const int q   = tid & 3;        // k-quarter

    __shared__ float x_s[TT];                       // 16 KB
    __shared__ __align__(16) _Float16 h0_h[HH];     // h0(t-1), fp16
    __shared__ __align__(16) _Float16 h1_h[HH];     // h1(t-2), fp16
    __shared__ float g0_s[4 * HH];                  // L0 gate activations (fp32)
    __shared__ float g1_s[4 * HH];                  // L1 gate activations (fp32)

    for (int t = tid; t < TT; t += 1024) x_s[t] = x[(size_t)b * TT + t];

    // 3 quarter-rows of weights -> fp16 packed VGPRs (24 half2).
    h2 w0[KQ / 2], wi1[KQ / 2], wh1[KQ / 2];
    {
        const float4* p0 = (const float4*)(W_hh0 + r * HH + q * KQ);
        const float4* p1 = (const float4*)(W_ih1 + r * HH + q * KQ);
        const float4* p2 = (const float4*)(W_hh1 + r * HH + q * KQ);
        #pragma unroll
        for (int k = 0; k < KQ / 4; ++k) {
            float4 v0 = p0[k], v1 = p1[k], v2 = p2[k];
            w0 [2*k+0] = h2{(_Float16)v0.x, (_Float16)v0.y};
            w0 [2*k+1] = h2{(_Float16)v0.z, (_Float16)v0.w};
            wi1[2*k+0] = h2{(_Float16)v1.x, (_Float16)v1.y};
            wi1[2*k+1] = h2{(_Float16)v1.z, (_Float16)v1.w};
            wh1[2*k+0] = h2{(_Float16)v2.x, (_Float16)v2.y};
            wh1[2*k+1] = h2{(_Float16)v2.z, (_Float16)v2.w};
        }
    }
    // PIN: make weight values opaque so LLVM cannot sink/remat the loads
    // into the t-loop (R5: it did, costing ~1750 cyc/step of L2 traffic).
    #pragma unroll
    for (int k = 0; k < KQ / 2; ++k) {
        asm volatile("" : "+v"(w0[k]), "+v"(wi1[k]), "+v"(wh1[k]));
    }

    const float wx  = W_ih0[r];
    const float bb0 = b_ih0[r] + b_hh0[r];
    const float bb1 = b_ih1[r] + b_hh1[r];
    const int gate_type = r >> 6;      // wave-uniform (16 rows/wave)

    float c0 = 0.f, c1 = 0.f;          // c0 live in wave0, c1 in wave1
    if (tid < HH) { h0_h[tid] = (_Float16)0.f; h1_h[tid] = (_Float16)0.f; }
    __syncthreads();

    const float4* h0v = (const float4*)h0_h;   // 8 halves per float4
    const float4* h1v = (const float4*)h1_h;

    // TT+1 iterations: L0 active for t<TT, L1 (one step behind) for t>0.
    for (int t = 0; t <= TT; ++t) {
        const float xt = x_s[(t < TT) ? t : 0];   // broadcast; unused at t=TT

        float acc0 = (q == 0) ? fmaf(xt, wx, bb0) : 0.f;
        float a1a  = (q == 0) ? bb1 : 0.f;        // W_ih1 . h0 chain
        float a1b  = 0.f;                         // W_hh1 . h1 chain

        // This thread's 16-half slices of h0 and h1 (2x b128 broadcast each).
        float4 H0a = h0v[q * 2 + 0], H0b = h0v[q * 2 + 1];
        float4 H1a = h1v[q * 2 + 0], H1b = h1v[q * 2 + 1];
        const h2* ph0 = (const h2*)&H0a;
        const h2* ph1 = (const h2*)&H1a;

        #pragma unroll
        for (int j = 0; j < 4; ++j) {
            acc0 = FDOT2(w0 [j], ph0[j], acc0);
            a1a  = FDOT2(wi1[j], ph0[j], a1a);
            a1b  = FDOT2(wh1[j], ph1[j], a1b);
        }
        const h2* ph0b = (const h2*)&H0b;
        const h2* ph1b = (const h2*)&H1b;
        #pragma unroll
        for (int j = 0; j < 4; ++j) {
            acc0 = FDOT2(w0 [4 + j], ph0b[j], acc0);
            a1a  = FDOT2(wi1[4 + j], ph0b[j], a1a);
            a1b  = FDOT2(wh1[4 + j], ph1b[j], a1b);
        }
        float acc1 = a1a + a1b;

        // Quad reduce (lanes 4r..4r+3, DPP).
        acc0 += __shfl_xor(acc0, 1);
        acc0 += __shfl_xor(acc0, 2);
        acc1 += __shfl_xor(acc1, 1);
        acc1 += __shfl_xor(acc1, 2);
        if (q == 0) {
            g0_s[r] = (gate_type == 2) ? ftanh(acc0) : fsig(acc0);
            g1_s[r] = (gate_type == 2) ? ftanh(acc1) : fsig(acc1);
        }
        __syncthreads();                          // B1: gates visible; h reads drained

        if (tid < HH) {                           // wave 0: L0 cell (time t)
            if (t < TT) {
                float iv = g0_s[tid];
                float fv = g0_s[HH + tid];
                float gv = g0_s[2 * HH + tid];
                float ov = g0_s[3 * HH + tid];
                c0 = fmaf(fv, c0, iv * gv);
                h0_h[tid] = (_Float16)(ov * ftanh(c0));
            }
        } else if (tid < 2 * HH) {                // wave 1: L1 cell (time t-1)
            if (t > 0) {
                int j = tid - HH;
                float iv = g1_s[j];
                float fv = g1_s[HH + j];
                float gv = g1_s[2 * HH + j];
                float ov = g1_s[3 * HH + j];
                c1 = fmaf(fv, c1, iv * gv);
                h1_h[j] = (_Float16)(ov * ftanh(c1));
            }
        }
        __syncthreads();                          // B2: new h0/h1 visible
    }

    // FC on final h1 = h1(TT-1): out[b, e] = W_fc[e,:] . h1 + b_fc[e]
    if (tid < EE) {
        float acc = b_fc[tid];
        const float4* wf = (const float4*)(W_fc + tid * HH);
        #pragma unroll
        for (int k = 0; k < HH / 4; ++k) {
            float4 v = wf[k];
            acc = fmaf(v.x, (float)h1_h[4*k+0], acc);
            acc = fmaf(v.y, (float)h1_h[4*k+1], acc);
            acc = fmaf(v.z, (float)h1_h[4*k+2], acc);
            acc = fmaf(v.w, (float)h1_h[4*k+3], acc);
        }
        out[(size_t)b * EE + tid] = acc;
    }
}

extern "C" void kernel_launch(void* const* d_in, const int* in_sizes, int n_in,
                              void* d_out, int out_size, void* d_ws, size_t ws_size,
                              hipStream_t stream) {
    const float* x     = (const float*)d_in[0];
    const float* W_ih0 = (const float*)d_in[1];
    const float* W_hh0 = (const float*)d_in[2];
    const float* b_ih0 = (const float*)d_in[3];
    const float* b_hh0 = (const float*)d_in[4];
    const float* W_ih1 = (const float*)d_in[5];
    const float* W_hh1 = (const float*)d_in[6];
    const float* b_ih1 = (const float*)d_in[7];
    const float* b_hh1 = (const float*)d_in[8];
    const float* W_fc  = (const float*)d_in[9];
    const float* b_fc  = (const float*)d_in[10];
    float* out = (float*)d_out;

    lstm2_fc_kernel<<<dim3(NB), dim3(1024), 0, stream>>>(
        x, W_ih0, W_hh0, b_ih0, b_hh0, W_ih1, W_hh1, b_ih1, b_hh1, W_fc, b_fc, out);
}